// Round 7
// baseline (912.753 us; speedup 1.0000x reference)
//
#include <hip/hip_runtime.h>
#include <hip/hip_bf16.h>

typedef unsigned short u16;
typedef __attribute__((ext_vector_type(8))) short short8;
typedef __attribute__((ext_vector_type(4))) float f32x4;

#define DIM 2048
#define HID 1408
#define NE 16
#define NTOK 2048
#define TOPK_ 4
#define SHID 2816
#define CAPROWS 10240
#define NSLOT 96                   // routed x-slots per fused dispatch (96 % 8 == 0)
#define AUX_IDX (2048 * 2048)

__device__ inline u16 f2bf(float f) {
  __bf16 h = (__bf16)f;                 // RNE hardware convert
  return __builtin_bit_cast(u16, h);
}

__device__ inline void gload_lds16(const void* g, void* l) {
  __builtin_amdgcn_global_load_lds(
      (const __attribute__((address_space(1))) unsigned int*)g,
      (__attribute__((address_space(3))) unsigned int*)l, 16, 0, 0);
}

// ---------------- gate phase 1: f64 logits, no atomics ----------------
__global__ __launch_bounds__(256) void gate_dots_kernel(
    const float* __restrict__ x, const float* __restrict__ gw,
    double* __restrict__ logits) {
  int t = blockIdx.x;
  const float* xt = x + (size_t)t * DIM;
  __shared__ double red[NE][4];
  int lane = threadIdx.x & 63, wid = threadIdx.x >> 6;
  for (int e = 0; e < NE; ++e) {
    const float* w = gw + e * DIM;
    double p = 0.0;
    for (int d = threadIdx.x; d < DIM; d += 256)
      p += (double)xt[d] * (double)w[d];
#pragma unroll
    for (int s = 32; s; s >>= 1) p += __shfl_xor(p, s);
    if (lane == 0) red[e][wid] = p;
  }
  __syncthreads();
  if (threadIdx.x < NE) {
    int e = threadIdx.x;
    logits[(size_t)t * NE + e] = red[e][0] + red[e][1] + red[e][2] + red[e][3];
  }
}

// ---------------- gate phase 2: per-token softmax + top-4 ----------------
__global__ __launch_bounds__(256) void topk_kernel(
    const double* __restrict__ logits,
    int* __restrict__ idxb, float* __restrict__ wtb,
    int* __restrict__ counts, float* __restrict__ ssum) {
  __shared__ int lcnt[NE];
  __shared__ float lsum[NE];
  if (threadIdx.x < NE) { lcnt[threadIdx.x] = 0; lsum[threadIdx.x] = 0.f; }
  __syncthreads();
  int t = blockIdx.x * 256 + threadIdx.x;
  int lane = threadIdx.x & 63;
  double sc[NE];
  double m = -1e300;
#pragma unroll
  for (int e = 0; e < NE; ++e) {
    sc[e] = logits[(size_t)t * NE + e];
    if (sc[e] > m) m = sc[e];
  }
  double s = 0.0;
#pragma unroll
  for (int e = 0; e < NE; ++e) { sc[e] = exp(sc[e] - m); s += sc[e]; }
  double inv = 1.0 / s;
#pragma unroll
  for (int e = 0; e < NE; ++e) sc[e] *= inv;
  unsigned used = 0;
  for (int k = 0; k < TOPK_; ++k) {
    int be = 0; double bv = -1.0;
#pragma unroll
    for (int e = 0; e < NE; ++e)
      if (!((used >> e) & 1u) && sc[e] > bv) { bv = sc[e]; be = e; }
    used |= 1u << be;
    idxb[t * TOPK_ + k] = be;
    wtb[t * TOPK_ + k] = (float)bv;     // ROUTE_SCALE = 1
    atomicAdd(&lcnt[be], 1);
  }
#pragma unroll
  for (int e = 0; e < NE; ++e) {
    float v = (float)sc[e];
#pragma unroll
    for (int sft = 32; sft; sft >>= 1) v += __shfl_xor(v, sft);
    if (lane == 0) atomicAdd(&lsum[e], v);
  }
  __syncthreads();
  if (threadIdx.x < NE) {
    atomicAdd(&counts[threadIdx.x], lcnt[threadIdx.x]);
    atomicAdd(&ssum[threadIdx.x], lsum[threadIdx.x]);
  }
}

// -------- segment offsets (128-padded), XCD-grouped routed slot map, aux loss --------
// Expert-ordered routed tile i -> slot (i/12) + (i%12)*8 (bijective on [0,96)):
// 12 consecutive same-expert tiles share one XCD (slot % 8 constant).
__global__ __launch_bounds__(256) void setup_kernel(
    const int* __restrict__ counts, int* __restrict__ off, int* __restrict__ cap,
    const float* __restrict__ ssum, int* __restrict__ perm, float* __restrict__ pwt,
    float* __restrict__ aux_out,
    int* __restrict__ rE, int* __restrict__ rM0) {
  for (int i = threadIdx.x; i < NSLOT; i += 256) rE[i] = -1;
  __syncthreads();
  if (threadIdx.x == 0) {
    int o = 0; double aux = 0.0; int nt = 0;
    for (int e = 0; e < NE; ++e) {
      off[e] = o;
      int c = (counts[e] + 127) & ~127;
      cap[e] = c;
      for (int t = 0; t < (c >> 7); ++t) {
        int slot = (nt / 12) + (nt % 12) * 8;
        rE[slot] = e;
        rM0[slot] = o + t * 128;
        ++nt;
      }
      o += c;
      aux += ((double)counts[e] / (NTOK * TOPK_)) * ((double)ssum[e] / NTOK);
    }
    aux_out[0] = (float)(NE * aux);
  }
  for (int i = threadIdx.x; i < CAPROWS; i += 256) { perm[i] = 0; pwt[i] = 0.f; }
}

__global__ __launch_bounds__(256) void scatter_kernel(
    const int* __restrict__ idxb, const float* __restrict__ wtb,
    const int* __restrict__ off, int* __restrict__ cursor,
    int* __restrict__ perm, float* __restrict__ pwt) {
  int t = blockIdx.x * 256 + threadIdx.x;
  if (t >= NTOK) return;
  for (int k = 0; k < TOPK_; ++k) {
    int e = idxb[t * TOPK_ + k];
    int s = atomicAdd(&cursor[e], 1);
    int p = off[e] + s;
    perm[p] = t;
    pwt[p] = wtb[t * TOPK_ + k];
  }
}

// ---------------- f32 -> bf16 stream convert (x only) ----------------
__global__ __launch_bounds__(256) void cvtN_kernel(const float* __restrict__ in,
                                                   u16* __restrict__ out, long n) {
  long stride = (long)gridDim.x * 2048;
  for (long i = ((long)blockIdx.x * 256 + threadIdx.x) * 8; i < n; i += stride) {
    float4 a = *(const float4*)(in + i);
    float4 b = *(const float4*)(in + i + 4);
    union { u16 u[8]; uint4 v; } o;
    o.u[0] = f2bf(a.x); o.u[1] = f2bf(a.y); o.u[2] = f2bf(a.z); o.u[3] = f2bf(a.w);
    o.u[4] = f2bf(b.x); o.u[5] = f2bf(b.y); o.u[6] = f2bf(b.z); o.u[7] = f2bf(b.w);
    *(uint4*)(out + i) = o.v;
  }
}

// ============ fused multi-GEMM, dbuf deep-prefetch pipeline ============
// 128M x 64N(-per-B) tile, BK=64, LDS double-buffered, 1 barrier / K-step:
//   [issue stageA(t+1) + loadB(t+1)] -> compute(t) -> writeB(t+1) -> barrier
// A-load latency covered by compute+writeB (barrier's vmcnt(0) is the wait);
// B-reg latency covered by compute (compiler waitcnt at writeB's first use).
//
// PHASE 1 (DUAL): x<96: routed h tile (gather, B=w1/w3+e, C=hbuf, 22 n-tiles)
//                 x>=96: shared h tile (B=sw1/sw3, C=hsb, 44 n-tiles folded 2-per-x)
// PHASE 2:        x<96: routed combine (A=hbuf, B=w2+e, atomicAdd into out * pwt)
//                 x>=96: z (A=hsb, B=sw2, atomicAdd into zeroed out)
template <int PHASE>
__global__ __launch_bounds__(256) void mgemm_kernel(
    const u16* __restrict__ xb,
    const u16* __restrict__ hbuf, const u16* __restrict__ hsb,
    const float* __restrict__ WrA, const float* __restrict__ WrB,   // w1,w3 | w2,-
    const float* __restrict__ WsA, const float* __restrict__ WsB,   // sw1,sw3 | sw2,-
    float* __restrict__ out,
    const int* __restrict__ rE, const int* __restrict__ rM0,
    const int* __restrict__ seg_off, const int* __restrict__ seg_cnt,
    const int* __restrict__ perm, const float* __restrict__ pwt) {
  constexpr bool DUAL = (PHASE == 1);
  int x = blockIdx.x, y = blockIdx.y;
  bool routed = (x < NSLOT);
  const u16* A; const float *B1, *B3 = nullptr; u16* Cb = nullptr;
  int lda, K, n0, m0, ldc, rowlim = 0;
  bool gather = false;
  if (routed) {
    int e = rE[x];
    if (e < 0) return;
    m0 = rM0[x];
    if (PHASE == 1) {
      if (y >= HID / 64) return;
      A = xb; lda = DIM; K = DIM; gather = true;
      B1 = WrA + (long)e * HID * DIM;
      B3 = WrB + (long)e * HID * DIM;
      n0 = y * 64; Cb = (u16*)hbuf; ldc = HID;
    } else {
      A = hbuf; lda = HID; K = HID;
      B1 = WrA + (long)e * DIM * HID;
      n0 = y * 64; ldc = DIM;
      rowlim = seg_off[e] + seg_cnt[e];
    }
  } else {
    if (PHASE == 1) {
      int j = (x - NSLOT) >> 1, sub = x & 1;
      m0 = j * 128;
      A = xb; lda = DIM; K = DIM;
      B1 = WsA; B3 = WsB;
      n0 = (y + sub * 22) * 64;        // 44 shared n-tiles folded into 32 x-slots
      Cb = (u16*)hsb; ldc = SHID;
    } else {
      int j = x - NSLOT;
      m0 = j * 128;
      A = hsb; lda = SHID; K = SHID;
      B1 = WsA;
      n0 = y * 64; ldc = DIM;
    }
  }
  int ldb = K;   // all B matrices have row length == K

  __shared__ u16 As[2][128 * 64];                 // 2 x 16 KB
  __shared__ u16 Bs1[2][64 * 64];                 // 2 x 8 KB
  __shared__ u16 Bs3[DUAL ? 2 : 1][DUAL ? 64 * 64 : 1];

  int tid = threadIdx.x;
  int lane = tid & 63;
  int wid = tid >> 6;
  int wr = wid >> 1, wc = wid & 1;

  f32x4 acc1[4][2], acc3[4][2];
#pragma unroll
  for (int mi = 0; mi < 4; ++mi)
#pragma unroll
    for (int ni = 0; ni < 2; ++ni) {
      acc1[mi][ni] = (f32x4){0.f, 0.f, 0.f, 0.f};
      acc3[mi][ni] = (f32x4){0.f, 0.f, 0.f, 0.f};
    }

  // A staging: thread -> 16B chunk; LDS dest wave-uniform base + lane*16 (linear)
  int ar = tid >> 3;          // 0..31
  int ac = (tid & 7) * 8;     // bf16 col
  long abase[4];
#pragma unroll
  for (int it = 0; it < 4; ++it) {
    int row = m0 + it * 32 + ar;
    int rid = gather ? perm[row] : row;
    abase[it] = (long)rid * lda + ac;
  }
  // B staging: 64 rows x 64 f32 per matrix; thread -> 4 float4 per matrix
  int brr = tid >> 4;         // 0..15
  int bsl = (tid & 15) * 4;   // f32 col
  long bbase[4];
#pragma unroll
  for (int it = 0; it < 4; ++it)
    bbase[it] = (long)(n0 + it * 16 + brr) * ldb + bsl;

  float4 r1[4], r3[4];

  auto stageA = [&](int buf, int k0) {
#pragma unroll
    for (int it = 0; it < 4; ++it)
      gload_lds16(A + abase[it] + k0, &As[buf][(it * 32 + ar) * 64 + ac]);
  };
  auto loadB = [&](int k0) {
#pragma unroll
    for (int it = 0; it < 4; ++it) r1[it] = *(const float4*)(B1 + bbase[it] + k0);
    if (DUAL) {
#pragma unroll
      for (int it = 0; it < 4; ++it) r3[it] = *(const float4*)(B3 + bbase[it] + k0);
    }
  };
  auto writeB = [&](int buf) {
#pragma unroll
    for (int it = 0; it < 4; ++it) {
      int lo = (it * 16 + brr) * 64 + bsl;
      ushort4 o;
      o.x = f2bf(r1[it].x); o.y = f2bf(r1[it].y); o.z = f2bf(r1[it].z); o.w = f2bf(r1[it].w);
      *(ushort4*)&Bs1[buf][lo] = o;
      if (DUAL) {
        ushort4 q;
        q.x = f2bf(r3[it].x); q.y = f2bf(r3[it].y); q.z = f2bf(r3[it].z); q.w = f2bf(r3[it].w);
        *(ushort4*)&Bs3[buf][lo] = q;
      }
    }
  };

  // prologue: tile 0 fully staged
  loadB(0);
  stageA(0, 0);
  writeB(0);
  __syncthreads();                       // vmcnt(0)+lgkmcnt(0) drain -> tile 0 ready

  int NT = K >> 6;
  for (int t = 0; t < NT; ++t) {
    int cur = t & 1, nxt = cur ^ 1;
    bool pf = (t + 1 < NT);
    if (pf) {
      stageA(nxt, (t + 1) << 6);         // async A(t+1): latency covered to barrier
      loadB((t + 1) << 6);               // B(t+1) -> regs: covered by compute
    }
#pragma unroll
    for (int kk = 0; kk < 64; kk += 32) {
      short8 af[4], b1f[2], b3f[2];
#pragma unroll
      for (int i = 0; i < 4; ++i)
        af[i] = *(const short8*)&As[cur][(wr * 64 + i * 16 + (lane & 15)) * 64 + kk + (lane >> 4) * 8];
#pragma unroll
      for (int i = 0; i < 2; ++i)
        b1f[i] = *(const short8*)&Bs1[cur][(wc * 32 + i * 16 + (lane & 15)) * 64 + kk + (lane >> 4) * 8];
      if (DUAL) {
#pragma unroll
        for (int i = 0; i < 2; ++i)
          b3f[i] = *(const short8*)&Bs3[cur][(wc * 32 + i * 16 + (lane & 15)) * 64 + kk + (lane >> 4) * 8];
      }
#pragma unroll
      for (int mi = 0; mi < 4; ++mi)
#pragma unroll
        for (int ni = 0; ni < 2; ++ni) {
          acc1[mi][ni] = __builtin_amdgcn_mfma_f32_16x16x32_bf16(af[mi], b1f[ni], acc1[mi][ni], 0, 0, 0);
          if (DUAL)
            acc3[mi][ni] = __builtin_amdgcn_mfma_f32_16x16x32_bf16(af[mi], b3f[ni], acc3[mi][ni], 0, 0, 0);
        }
    }
    if (pf) writeB(nxt);                 // waits B regs (issued one compute-phase ago)
    __syncthreads();                     // drains A(t+1) gloads; publishes tile t+1
  }

  int rbase = m0 + wr * 64 + (lane >> 4) * 4;
  int cbase = n0 + wc * 32 + (lane & 15);
#pragma unroll
  for (int mi = 0; mi < 4; ++mi) {
#pragma unroll
    for (int ni = 0; ni < 2; ++ni) {
      int col = cbase + ni * 16;
#pragma unroll
      for (int r = 0; r < 4; ++r) {
        int row = rbase + mi * 16 + r;
        float v = acc1[mi][ni][r];
        if (PHASE == 1) {
          float a3 = acc3[mi][ni][r];
          float sg = v / (1.f + __expf(-v));
          Cb[(long)row * ldc + col] = f2bf(sg * a3);
        } else {
          if (routed) {
            if (row < rowlim)
              atomicAdd(&out[(long)perm[row] * DIM + col], v * pwt[row]);
          } else {
            atomicAdd(&out[(long)row * DIM + col], v);   // z into zeroed out
          }
        }
      }
    }
  }
}

extern "C" void kernel_launch(void* const* d_in, const int* in_sizes, int n_in,
                              void* d_out, int out_size, void* d_ws, size_t ws_size,
                              hipStream_t stream) {
  (void)in_sizes; (void)n_in; (void)out_size; (void)ws_size;
  const float* x   = (const float*)d_in[0];
  const float* gw  = (const float*)d_in[1];
  const float* w1  = (const float*)d_in[2];
  const float* w2  = (const float*)d_in[3];
  const float* w3  = (const float*)d_in[4];
  const float* sw1 = (const float*)d_in[5];
  const float* sw2 = (const float*)d_in[6];
  const float* sw3 = (const float*)d_in[7];
  float* out = (float*)d_out;
  char* ws = (char*)d_ws;

  int*   counts = (int*)(ws + 0);
  int*   cursor = (int*)(ws + 64);
  int*   off    = (int*)(ws + 128);
  int*   cap    = (int*)(ws + 192);
  float* ssum   = (float*)(ws + 256);
  int*   rE     = (int*)(ws + 1024);
  int*   rM0    = (int*)(ws + 2048);
  int*   idxb   = (int*)(ws + 4096);
  float* wtb    = (float*)(ws + 4096 + 32768);
  int*   perm   = (int*)(ws + 4096 + 65536);
  float* pwt    = (float*)(ws + 4096 + 65536 + 40960);
  u16*   xb     = (u16*)(ws + 262144);                 // 2048x2048 bf16
  double* logits = (double*)(ws + 8650752);            // 2048x16 f64
  u16*   hbuf   = (u16*)(ws + 16777216);               // 10240x1408 bf16
  u16*   hsb    = (u16*)(ws + 45613056);               // 2048x2816 bf16

  hipMemsetAsync(ws, 0, 512, stream);
  hipMemsetAsync(out, 0, (size_t)NTOK * DIM * sizeof(float), stream);  // z/y accumulate base
  gate_dots_kernel<<<dim3(NTOK), dim3(256), 0, stream>>>(x, gw, logits);
  topk_kernel<<<dim3(NTOK / 256), dim3(256), 0, stream>>>(logits, idxb, wtb, counts, ssum);
  setup_kernel<<<dim3(1), dim3(256), 0, stream>>>(counts, off, cap, ssum, perm, pwt,
                                                  out + AUX_IDX, rE, rM0);
  scatter_kernel<<<dim3(8), dim3(256), 0, stream>>>(idxb, wtb, off, cursor, perm, pwt);
  cvtN_kernel<<<dim3(2048), dim3(256), 0, stream>>>(x, xb, (long)NTOK * DIM);

  // phase 1: routed h (x<96, 22 n-tiles) + shared h (x in [96,128), 44 n-tiles folded)
  mgemm_kernel<1><<<dim3(NSLOT + 32, HID / 64), dim3(256), 0, stream>>>(
      xb, hbuf, hsb, w1, w3, sw1, sw3, out, rE, rM0, off, counts, perm, pwt);
  // phase 2: routed combine (x<96) + z (x in [96,112)), both 32 n-tiles, atomic into out
  mgemm_kernel<2><<<dim3(NSLOT + 16, DIM / 64), dim3(256), 0, stream>>>(
      xb, hbuf, hsb, w2, nullptr, sw2, nullptr, out, rE, rM0, off, counts, perm, pwt);
}

// Round 8
// 654.478 us; speedup vs baseline: 1.3946x; 1.3946x over previous
//
#include <hip/hip_runtime.h>
#include <hip/hip_bf16.h>

typedef unsigned short u16;
typedef __attribute__((ext_vector_type(8))) short short8;
typedef __attribute__((ext_vector_type(4))) float f32x4;

#define DIM 2048
#define HID 1408
#define NE 16
#define NTOK 2048
#define TOPK_ 4
#define SHID 2816
#define CAPROWS 10240
#define MAXTILES (CAPROWS / 128)   // 80; 80 % 8 == 0 so XCD == slot % 8
#define AUX_IDX (2048 * 2048)

__device__ inline u16 f2bf(float f) {
  __bf16 h = (__bf16)f;                 // RNE hardware convert
  return __builtin_bit_cast(u16, h);
}

__device__ inline void gload_lds16(const void* g, void* l) {
  __builtin_amdgcn_global_load_lds(
      (const __attribute__((address_space(1))) unsigned int*)g,
      (__attribute__((address_space(3))) unsigned int*)l, 16, 0, 0);
}

// ---------------- gate phase 1: f64 logits, no atomics ----------------
__global__ __launch_bounds__(256) void gate_dots_kernel(
    const float* __restrict__ x, const float* __restrict__ gw,
    double* __restrict__ logits) {
  int t = blockIdx.x;
  const float* xt = x + (size_t)t * DIM;
  __shared__ double red[NE][4];
  int lane = threadIdx.x & 63, wid = threadIdx.x >> 6;
  for (int e = 0; e < NE; ++e) {
    const float* w = gw + e * DIM;
    double p = 0.0;
    for (int d = threadIdx.x; d < DIM; d += 256)
      p += (double)xt[d] * (double)w[d];
#pragma unroll
    for (int s = 32; s; s >>= 1) p += __shfl_xor(p, s);
    if (lane == 0) red[e][wid] = p;
  }
  __syncthreads();
  if (threadIdx.x < NE) {
    int e = threadIdx.x;
    logits[(size_t)t * NE + e] = red[e][0] + red[e][1] + red[e][2] + red[e][3];
  }
}

// ---------------- gate phase 2: per-token softmax + top-4 ----------------
__global__ __launch_bounds__(256) void topk_kernel(
    const double* __restrict__ logits,
    int* __restrict__ idxb, float* __restrict__ wtb,
    int* __restrict__ counts, float* __restrict__ ssum) {
  __shared__ int lcnt[NE];
  __shared__ float lsum[NE];
  if (threadIdx.x < NE) { lcnt[threadIdx.x] = 0; lsum[threadIdx.x] = 0.f; }
  __syncthreads();
  int t = blockIdx.x * 256 + threadIdx.x;
  int lane = threadIdx.x & 63;
  double sc[NE];
  double m = -1e300;
#pragma unroll
  for (int e = 0; e < NE; ++e) {
    sc[e] = logits[(size_t)t * NE + e];
    if (sc[e] > m) m = sc[e];
  }
  double s = 0.0;
#pragma unroll
  for (int e = 0; e < NE; ++e) { sc[e] = exp(sc[e] - m); s += sc[e]; }
  double inv = 1.0 / s;
#pragma unroll
  for (int e = 0; e < NE; ++e) sc[e] *= inv;
  unsigned used = 0;
  for (int k = 0; k < TOPK_; ++k) {
    int be = 0; double bv = -1.0;
#pragma unroll
    for (int e = 0; e < NE; ++e)
      if (!((used >> e) & 1u) && sc[e] > bv) { bv = sc[e]; be = e; }
    used |= 1u << be;
    idxb[t * TOPK_ + k] = be;
    wtb[t * TOPK_ + k] = (float)bv;     // ROUTE_SCALE = 1
    atomicAdd(&lcnt[be], 1);
  }
#pragma unroll
  for (int e = 0; e < NE; ++e) {
    float v = (float)sc[e];
#pragma unroll
    for (int sft = 32; sft; sft >>= 1) v += __shfl_xor(v, sft);
    if (lane == 0) atomicAdd(&lsum[e], v);
  }
  __syncthreads();
  if (threadIdx.x < NE) {
    atomicAdd(&counts[threadIdx.x], lcnt[threadIdx.x]);
    atomicAdd(&ssum[threadIdx.x], lsum[threadIdx.x]);
  }
}

// -------- segment offsets (128-padded), XCD-grouped tile map, aux loss --------
// Expert-ordered tile i -> slot (i/10) + (i%10)*8 (bijective on [0,80)):
// 10 consecutive same-expert tiles share one XCD (slot % 8 constant).
__global__ __launch_bounds__(256) void setup_kernel(
    const int* __restrict__ counts, int* __restrict__ off, int* __restrict__ cap,
    const float* __restrict__ ssum, int* __restrict__ perm, float* __restrict__ pwt,
    float* __restrict__ aux_out,
    int* __restrict__ tile2e, int* __restrict__ tile2m0) {
  for (int i = threadIdx.x; i < MAXTILES; i += 256) tile2e[i] = -1;
  __syncthreads();
  if (threadIdx.x == 0) {
    int o = 0; double aux = 0.0; int nt = 0;
    for (int e = 0; e < NE; ++e) {
      off[e] = o;
      int c = (counts[e] + 127) & ~127;
      cap[e] = c;
      for (int t = 0; t < (c >> 7); ++t) {
        int slot = (nt / 10) + (nt % 10) * 8;
        tile2e[slot] = e;
        tile2m0[slot] = o + t * 128;
        ++nt;
      }
      o += c;
      aux += ((double)counts[e] / (NTOK * TOPK_)) * ((double)ssum[e] / NTOK);
    }
    aux_out[0] = (float)(NE * aux);
  }
  for (int i = threadIdx.x; i < CAPROWS; i += 256) { perm[i] = 0; pwt[i] = 0.f; }
}

__global__ __launch_bounds__(256) void scatter_kernel(
    const int* __restrict__ idxb, const float* __restrict__ wtb,
    const int* __restrict__ off, int* __restrict__ cursor,
    int* __restrict__ perm, float* __restrict__ pwt) {
  int t = blockIdx.x * 256 + threadIdx.x;
  if (t >= NTOK) return;
  for (int k = 0; k < TOPK_; ++k) {
    int e = idxb[t * TOPK_ + k];
    int s = atomicAdd(&cursor[e], 1);
    int p = off[e] + s;
    perm[p] = t;
    pwt[p] = wtb[t * TOPK_ + k];
  }
}

// ---------------- f32 -> bf16 stream convert (x only) ----------------
__global__ __launch_bounds__(256) void cvtN_kernel(const float* __restrict__ in,
                                                   u16* __restrict__ out, long n) {
  long stride = (long)gridDim.x * 2048;
  for (long i = ((long)blockIdx.x * 256 + threadIdx.x) * 8; i < n; i += stride) {
    float4 a = *(const float4*)(in + i);
    float4 b = *(const float4*)(in + i + 4);
    union { u16 u[8]; uint4 v; } o;
    o.u[0] = f2bf(a.x); o.u[1] = f2bf(a.y); o.u[2] = f2bf(a.z); o.u[3] = f2bf(a.w);
    o.u[4] = f2bf(b.x); o.u[5] = f2bf(b.y); o.u[6] = f2bf(b.z); o.u[7] = f2bf(b.w);
    *(uint4*)(out + i) = o.v;
  }
}

// ============ GEMM v6: gload_lds both operands + XOR bank swizzle ============
// A: bf16 128x64 tile (16 KB). B1/B3: f32 weights staged DIRECTLY 64x64 (16 KB ea).
// Single-buffered, 2 barriers/K-step (R4/m97 structure, best measured).
// Swizzle (rule #21: linear LDS dest + inverse-swizzled GLOBAL SOURCE + swizzled read):
//   A (8 chunks/row):  chunk' = chunk ^ (row&7)
//   B (16 chunks/row): chunk' = chunk ^ (row&7)
// Read-side banks then spread over 8 banks (2-way residual = free, m136).
// B fragments: 2x ds_read_b128 (f32x4 pair) + in-register cvt to bf16x8.
// EPI 0 (DUAL): Cb = bf16( silu(acc1) * acc3 )
// EPI 1: C0 = acc1 (plain f32 store)
// EPI 2: atomicAdd(C0[perm[row]*ldc0+col], acc1 * pwt[row]) for valid rows
template <bool GATHER, bool DUAL, int EPI>
__global__ __launch_bounds__(256) void gemm6_kernel(
    const u16* __restrict__ A, int lda,
    const float* __restrict__ B1, const float* __restrict__ B3,
    int ldb, long bstride, int K,
    const int* __restrict__ tile2e, const int* __restrict__ tile2m0,
    const int* __restrict__ seg_off, const int* __restrict__ seg_cnt,
    const int* __restrict__ perm, const float* __restrict__ pwt,
    float* __restrict__ C0, int ldc0,
    u16* __restrict__ Cb, int ldcb, int Mfixed) {
  int e, m0, rowlim;
  if (tile2e) {
    e = tile2e[blockIdx.x];
    if (e < 0) return;
    m0 = tile2m0[blockIdx.x];
    rowlim = seg_off[e] + seg_cnt[e];
  } else {
    e = 0;
    m0 = blockIdx.x * 128;
    if (m0 >= Mfixed) return;
    rowlim = Mfixed;
  }
  int n0 = blockIdx.y * 64;
  const float* Bb1 = B1 + (long)e * bstride;
  const float* Bb3 = DUAL ? (B3 + (long)e * bstride) : nullptr;

  __shared__ u16 As[128 * 64];                  // 16 KB bf16
  __shared__ float Bs1[64 * 64];                // 16 KB f32
  __shared__ float Bs3[DUAL ? 64 * 64 : 1];     // 16 KB if DUAL

  int tid = threadIdx.x;
  int lane = tid & 63;
  int wid = tid >> 6;
  int wr = wid >> 1, wc = wid & 1;

  f32x4 acc1[4][2], acc3[4][2];
#pragma unroll
  for (int mi = 0; mi < 4; ++mi)
#pragma unroll
    for (int ni = 0; ni < 2; ++ni) {
      acc1[mi][ni] = (f32x4){0.f, 0.f, 0.f, 0.f};
      acc3[mi][ni] = (f32x4){0.f, 0.f, 0.f, 0.f};
    }

  // ---- A staging: row = tid>>3 (+32/it), chunk = tid&7; source chunk XOR'd ----
  int sr = tid >> 3;          // 0..31
  int scA = tid & 7;          // 16B chunk in row (8 bf16)
  long abase[4];
#pragma unroll
  for (int it = 0; it < 4; ++it) {
    int row = m0 + it * 32 + sr;
    int rid = GATHER ? perm[row] : row;
    abase[it] = (long)rid * lda + ((scA ^ (sr & 7)) << 3);   // bf16 elems
  }
  // ---- B staging: row = tid>>4 (+16/it), chunk = tid&15; source chunk XOR'd ----
  int br = tid >> 4;          // 0..15
  int scB = tid & 15;         // 16B chunk in row (4 f32)
  long bbase[4];
#pragma unroll
  for (int it = 0; it < 4; ++it)
    bbase[it] = (long)(n0 + it * 16 + br) * ldb + ((scB ^ (br & 7)) << 2);  // f32 elems

  for (int k0 = 0; k0 < K; k0 += 64) {
#pragma unroll
    for (int it = 0; it < 4; ++it)
      gload_lds16(A + abase[it] + k0, &As[(it * 32 + sr) * 64 + scA * 8]);
#pragma unroll
    for (int it = 0; it < 4; ++it)
      gload_lds16(Bb1 + bbase[it] + k0, &Bs1[(it * 16 + br) * 64 + scB * 4]);
    if (DUAL) {
#pragma unroll
      for (int it = 0; it < 4; ++it)
        gload_lds16(Bb3 + bbase[it] + k0, &Bs3[(it * 16 + br) * 64 + scB * 4]);
    }
    __syncthreads();            // vmcnt(0) drain -> tile ready
#pragma unroll
    for (int kk = 0; kk < 64; kk += 32) {
      short8 af[4];
#pragma unroll
      for (int i = 0; i < 4; ++i) {
        int R = wr * 64 + i * 16 + (lane & 15);
        int c = (kk >> 3) + (lane >> 4);
        af[i] = *(const short8*)&As[R * 64 + ((c ^ (R & 7)) << 3)];
      }
      short8 b1f[2], b3f[2];
#pragma unroll
      for (int i = 0; i < 2; ++i) {
        int r = wc * 32 + i * 16 + (lane & 15);
        int cB = (kk >> 2) + ((lane >> 4) << 1);
        int s7 = r & 7;
        f32x4 lo = *(const f32x4*)&Bs1[r * 64 + ((cB ^ s7) << 2)];
        f32x4 hi = *(const f32x4*)&Bs1[r * 64 + (((cB + 1) ^ s7) << 2)];
        short8 f;
        f[0] = (short)f2bf(lo[0]); f[1] = (short)f2bf(lo[1]);
        f[2] = (short)f2bf(lo[2]); f[3] = (short)f2bf(lo[3]);
        f[4] = (short)f2bf(hi[0]); f[5] = (short)f2bf(hi[1]);
        f[6] = (short)f2bf(hi[2]); f[7] = (short)f2bf(hi[3]);
        b1f[i] = f;
        if (DUAL) {
          f32x4 lo3 = *(const f32x4*)&Bs3[r * 64 + ((cB ^ s7) << 2)];
          f32x4 hi3 = *(const f32x4*)&Bs3[r * 64 + (((cB + 1) ^ s7) << 2)];
          short8 g;
          g[0] = (short)f2bf(lo3[0]); g[1] = (short)f2bf(lo3[1]);
          g[2] = (short)f2bf(lo3[2]); g[3] = (short)f2bf(lo3[3]);
          g[4] = (short)f2bf(hi3[0]); g[5] = (short)f2bf(hi3[1]);
          g[6] = (short)f2bf(hi3[2]); g[7] = (short)f2bf(hi3[3]);
          b3f[i] = g;
        }
      }
#pragma unroll
      for (int mi = 0; mi < 4; ++mi)
#pragma unroll
        for (int ni = 0; ni < 2; ++ni) {
          acc1[mi][ni] = __builtin_amdgcn_mfma_f32_16x16x32_bf16(af[mi], b1f[ni], acc1[mi][ni], 0, 0, 0);
          if (DUAL)
            acc3[mi][ni] = __builtin_amdgcn_mfma_f32_16x16x32_bf16(af[mi], b3f[ni], acc3[mi][ni], 0, 0, 0);
        }
    }
    __syncthreads();            // all waves done reading before overwrite
  }

  int rbase = m0 + wr * 64 + (lane >> 4) * 4;
  int cbase = n0 + wc * 32 + (lane & 15);
#pragma unroll
  for (int mi = 0; mi < 4; ++mi) {
#pragma unroll
    for (int ni = 0; ni < 2; ++ni) {
      int col = cbase + ni * 16;
#pragma unroll
      for (int r = 0; r < 4; ++r) {
        int row = rbase + mi * 16 + r;
        float v = acc1[mi][ni][r];
        if (EPI == 0) {
          float a3 = acc3[mi][ni][r];
          float sg = v / (1.f + __expf(-v));
          Cb[(long)row * ldcb + col] = f2bf(sg * a3);
        } else if (EPI == 1) {
          C0[(long)row * ldc0 + col] = v;
        } else {
          if (row < rowlim) {
            atomicAdd(&C0[(long)perm[row] * ldc0 + col], v * pwt[row]);
          }
        }
      }
    }
  }
}

extern "C" void kernel_launch(void* const* d_in, const int* in_sizes, int n_in,
                              void* d_out, int out_size, void* d_ws, size_t ws_size,
                              hipStream_t stream) {
  (void)in_sizes; (void)n_in; (void)out_size; (void)ws_size;
  const float* x   = (const float*)d_in[0];
  const float* gw  = (const float*)d_in[1];
  const float* w1  = (const float*)d_in[2];
  const float* w2  = (const float*)d_in[3];
  const float* w3  = (const float*)d_in[4];
  const float* sw1 = (const float*)d_in[5];
  const float* sw2 = (const float*)d_in[6];
  const float* sw3 = (const float*)d_in[7];
  float* out = (float*)d_out;
  char* ws = (char*)d_ws;

  int*   counts = (int*)(ws + 0);
  int*   cursor = (int*)(ws + 64);
  int*   off    = (int*)(ws + 128);
  int*   cap    = (int*)(ws + 192);
  float* ssum   = (float*)(ws + 256);
  int*   tile2e = (int*)(ws + 1024);
  int*   tile2m0= (int*)(ws + 2048);
  int*   idxb   = (int*)(ws + 4096);
  float* wtb    = (float*)(ws + 4096 + 32768);
  int*   perm   = (int*)(ws + 4096 + 65536);
  float* pwt    = (float*)(ws + 4096 + 65536 + 40960);
  u16*   xb     = (u16*)(ws + 262144);                 // 2048x2048 bf16
  double* logits = (double*)(ws + 8650752);            // 2048x16 f64
  u16*   hbuf   = (u16*)(ws + 16777216);               // 10240x1408 bf16
  u16*   hsb    = (u16*)(ws + 45613056);               // 2048x2816 bf16

  hipMemsetAsync(ws, 0, 512, stream);
  gate_dots_kernel<<<dim3(NTOK), dim3(256), 0, stream>>>(x, gw, logits);
  topk_kernel<<<dim3(NTOK / 256), dim3(256), 0, stream>>>(logits, idxb, wtb, counts, ssum);
  setup_kernel<<<dim3(1), dim3(256), 0, stream>>>(counts, off, cap, ssum, perm, pwt,
                                                  out + AUX_IDX, tile2e, tile2m0);
  scatter_kernel<<<dim3(8), dim3(256), 0, stream>>>(idxb, wtb, off, cursor, perm, pwt);
  cvtN_kernel<<<dim3(2048), dim3(256), 0, stream>>>(x, xb, (long)NTOK * DIM);

  // routed h = silu(gather(x)@w1^T) * (gather(x)@w3^T) -> bf16  [dual, f32 weights direct]
  gemm6_kernel<true, true, 0><<<dim3(MAXTILES, HID / 64), dim3(256), 0, stream>>>(
      xb, DIM, w1, w3, DIM, (long)HID * DIM, DIM, tile2e, tile2m0,
      off, counts, perm, pwt, nullptr, 0, hbuf, HID, 0);
  // shared hs = silu(x@sw1^T) * (x@sw3^T) -> bf16
  gemm6_kernel<false, true, 0><<<dim3(NTOK / 128, SHID / 64), dim3(256), 0, stream>>>(
      xb, DIM, sw1, sw3, DIM, 0, DIM, nullptr, nullptr,
      nullptr, nullptr, nullptr, nullptr, nullptr, 0, hsb, SHID, NTOK);
  // z = hs @ sw2^T  (plain f32 store into out)
  gemm6_kernel<false, false, 1><<<dim3(NTOK / 128, DIM / 64), dim3(256), 0, stream>>>(
      hsb, SHID, sw2, nullptr, SHID, 0, SHID, nullptr, nullptr,
      nullptr, nullptr, nullptr, nullptr, out, DIM, nullptr, 0, NTOK);
  // out += (h @ w2^T) * pwt   (atomic accumulate on top of z)
  gemm6_kernel<false, false, 2><<<dim3(MAXTILES, DIM / 64), dim3(256), 0, stream>>>(
      hbuf, HID, w2, nullptr, HID, (long)DIM * HID, HID, tile2e, tile2m0,
      off, counts, perm, pwt, out, DIM, nullptr, 0, 0);
}

// Round 9
// 642.682 us; speedup vs baseline: 1.4202x; 1.0184x over previous
//
#include <hip/hip_runtime.h>
#include <hip/hip_bf16.h>

typedef unsigned short u16;
typedef __attribute__((ext_vector_type(8))) short short8;
typedef __attribute__((ext_vector_type(4))) float f32x4;

#define DIM 2048
#define HID 1408
#define NE 16
#define NTOK 2048
#define TOPK_ 4
#define SHID 2816
#define CAPROWS 10240
#define MAXTILES (CAPROWS / 128)   // 80; 80 % 8 == 0 so XCD == slot % 8
#define AUX_IDX (2048 * 2048)

__device__ inline u16 f2bf(float f) {
  __bf16 h = (__bf16)f;                 // RNE hardware convert
  return __builtin_bit_cast(u16, h);
}

__device__ inline void gload_lds16(const void* g, void* l) {
  __builtin_amdgcn_global_load_lds(
      (const __attribute__((address_space(1))) unsigned int*)g,
      (__attribute__((address_space(3))) unsigned int*)l, 16, 0, 0);
}

// ---------------- gate phase 1: f64 logits, no atomics ----------------
__global__ __launch_bounds__(256) void gate_dots_kernel(
    const float* __restrict__ x, const float* __restrict__ gw,
    double* __restrict__ logits) {
  int t = blockIdx.x;
  const float* xt = x + (size_t)t * DIM;
  __shared__ double red[NE][4];
  int lane = threadIdx.x & 63, wid = threadIdx.x >> 6;
  for (int e = 0; e < NE; ++e) {
    const float* w = gw + e * DIM;
    double p = 0.0;
    for (int d = threadIdx.x; d < DIM; d += 256)
      p += (double)xt[d] * (double)w[d];
#pragma unroll
    for (int s = 32; s; s >>= 1) p += __shfl_xor(p, s);
    if (lane == 0) red[e][wid] = p;
  }
  __syncthreads();
  if (threadIdx.x < NE) {
    int e = threadIdx.x;
    logits[(size_t)t * NE + e] = red[e][0] + red[e][1] + red[e][2] + red[e][3];
  }
}

// ---------------- gate phase 2: per-token softmax + top-4 ----------------
__global__ __launch_bounds__(256) void topk_kernel(
    const double* __restrict__ logits,
    int* __restrict__ idxb, float* __restrict__ wtb,
    int* __restrict__ counts, float* __restrict__ ssum) {
  __shared__ int lcnt[NE];
  __shared__ float lsum[NE];
  if (threadIdx.x < NE) { lcnt[threadIdx.x] = 0; lsum[threadIdx.x] = 0.f; }
  __syncthreads();
  int t = blockIdx.x * 256 + threadIdx.x;
  int lane = threadIdx.x & 63;
  double sc[NE];
  double m = -1e300;
#pragma unroll
  for (int e = 0; e < NE; ++e) {
    sc[e] = logits[(size_t)t * NE + e];
    if (sc[e] > m) m = sc[e];
  }
  double s = 0.0;
#pragma unroll
  for (int e = 0; e < NE; ++e) { sc[e] = exp(sc[e] - m); s += sc[e]; }
  double inv = 1.0 / s;
#pragma unroll
  for (int e = 0; e < NE; ++e) sc[e] *= inv;
  unsigned used = 0;
  for (int k = 0; k < TOPK_; ++k) {
    int be = 0; double bv = -1.0;
#pragma unroll
    for (int e = 0; e < NE; ++e)
      if (!((used >> e) & 1u) && sc[e] > bv) { bv = sc[e]; be = e; }
    used |= 1u << be;
    idxb[t * TOPK_ + k] = be;
    wtb[t * TOPK_ + k] = (float)bv;     // ROUTE_SCALE = 1
    atomicAdd(&lcnt[be], 1);
  }
#pragma unroll
  for (int e = 0; e < NE; ++e) {
    float v = (float)sc[e];
#pragma unroll
    for (int sft = 32; sft; sft >>= 1) v += __shfl_xor(v, sft);
    if (lane == 0) atomicAdd(&lsum[e], v);
  }
  __syncthreads();
  if (threadIdx.x < NE) {
    atomicAdd(&counts[threadIdx.x], lcnt[threadIdx.x]);
    atomicAdd(&ssum[threadIdx.x], lsum[threadIdx.x]);
  }
}

// -------- segment offsets (128-padded), XCD-grouped tile map, aux loss --------
__global__ __launch_bounds__(256) void setup_kernel(
    const int* __restrict__ counts, int* __restrict__ off, int* __restrict__ cap,
    const float* __restrict__ ssum, int* __restrict__ perm, float* __restrict__ pwt,
    float* __restrict__ aux_out,
    int* __restrict__ tile2e, int* __restrict__ tile2m0) {
  for (int i = threadIdx.x; i < MAXTILES; i += 256) tile2e[i] = -1;
  __syncthreads();
  if (threadIdx.x == 0) {
    int o = 0; double aux = 0.0; int nt = 0;
    for (int e = 0; e < NE; ++e) {
      off[e] = o;
      int c = (counts[e] + 127) & ~127;
      cap[e] = c;
      for (int t = 0; t < (c >> 7); ++t) {
        int slot = (nt / 10) + (nt % 10) * 8;
        tile2e[slot] = e;
        tile2m0[slot] = o + t * 128;
        ++nt;
      }
      o += c;
      aux += ((double)counts[e] / (NTOK * TOPK_)) * ((double)ssum[e] / NTOK);
    }
    aux_out[0] = (float)(NE * aux);
  }
  for (int i = threadIdx.x; i < CAPROWS; i += 256) { perm[i] = 0; pwt[i] = 0.f; }
}

__global__ __launch_bounds__(256) void scatter_kernel(
    const int* __restrict__ idxb, const float* __restrict__ wtb,
    const int* __restrict__ off, int* __restrict__ cursor,
    int* __restrict__ perm, float* __restrict__ pwt) {
  int t = blockIdx.x * 256 + threadIdx.x;
  if (t >= NTOK) return;
  for (int k = 0; k < TOPK_; ++k) {
    int e = idxb[t * TOPK_ + k];
    int s = atomicAdd(&cursor[e], 1);
    int p = off[e] + s;
    perm[p] = t;
    pwt[p] = wtb[t * TOPK_ + k];
  }
}

// ---------------- f32 -> bf16 stream convert (x only) ----------------
__global__ __launch_bounds__(256) void cvtN_kernel(const float* __restrict__ in,
                                                   u16* __restrict__ out, long n) {
  long stride = (long)gridDim.x * 2048;
  for (long i = ((long)blockIdx.x * 256 + threadIdx.x) * 8; i < n; i += stride) {
    float4 a = *(const float4*)(in + i);
    float4 b = *(const float4*)(in + i + 4);
    union { u16 u[8]; uint4 v; } o;
    o.u[0] = f2bf(a.x); o.u[1] = f2bf(a.y); o.u[2] = f2bf(a.z); o.u[3] = f2bf(a.w);
    o.u[4] = f2bf(b.x); o.u[5] = f2bf(b.y); o.u[6] = f2bf(b.z); o.u[7] = f2bf(b.w);
    *(uint4*)(out + i) = o.v;
  }
}

// ====== GEMM v7: dbuf + counted vmcnt + raw barriers (T3/T4) ======
// A: bf16 128x64, gload_lds, source pre-swizzled (chunk ^= row&7), 2 x 16KB.
// B: f32 global -> regs (issued one iter early) -> cvt -> bf16 LDS (swizzled write), 2 x 8KB per matrix.
// Per iter: writeB(t) [implicit wait on B(t) regs, leaves A(t) flying];
//           loadB(t+1); stageA(t+1); vmcnt(12 dual / 8 single) waits ONLY A(t);
//           lgkmcnt(0); s_barrier; compute(t); s_barrier.
// Next tile's loads stay in flight across both barriers (no vmcnt(0) drain).
template <bool GATHER, bool DUAL, int EPI>
__global__ __launch_bounds__(256) void gemm7_kernel(
    const u16* __restrict__ A, int lda,
    const float* __restrict__ B1, const float* __restrict__ B3,
    int ldb, long bstride, int K,
    const int* __restrict__ tile2e, const int* __restrict__ tile2m0,
    const int* __restrict__ seg_off, const int* __restrict__ seg_cnt,
    const int* __restrict__ perm, const float* __restrict__ pwt,
    float* __restrict__ C0, int ldc0,
    u16* __restrict__ Cb, int ldcb, int Mfixed) {
  int e, m0, rowlim;
  if (tile2e) {
    e = tile2e[blockIdx.x];
    if (e < 0) return;
    m0 = tile2m0[blockIdx.x];
    rowlim = seg_off[e] + seg_cnt[e];
  } else {
    e = 0;
    m0 = blockIdx.x * 128;
    if (m0 >= Mfixed) return;
    rowlim = Mfixed;
  }
  int n0 = blockIdx.y * 64;
  const float* Bb1 = B1 + (long)e * bstride;
  const float* Bb3 = DUAL ? (B3 + (long)e * bstride) : nullptr;

  __shared__ u16 As[2][128 * 64];               // 2 x 16 KB
  __shared__ u16 Bs1[2][64 * 64];               // 2 x 8 KB
  __shared__ u16 Bs3[DUAL ? 2 : 1][DUAL ? 64 * 64 : 1];

  int tid = threadIdx.x;
  int lane = tid & 63;
  int wid = tid >> 6;
  int wr = wid >> 1, wc = wid & 1;

  f32x4 acc1[4][2], acc3[4][2];
#pragma unroll
  for (int mi = 0; mi < 4; ++mi)
#pragma unroll
    for (int ni = 0; ni < 2; ++ni) {
      acc1[mi][ni] = (f32x4){0.f, 0.f, 0.f, 0.f};
      acc3[mi][ni] = (f32x4){0.f, 0.f, 0.f, 0.f};
    }

  // ---- A staging: row=tid>>3 (+32/it), chunk=tid&7; SOURCE chunk XOR'd (rule #21) ----
  int sr = tid >> 3;
  int scA = tid & 7;
  long abase[4];
#pragma unroll
  for (int it = 0; it < 4; ++it) {
    int row = m0 + it * 32 + sr;
    int rid = GATHER ? perm[row] : row;
    abase[it] = (long)rid * lda + ((scA ^ (sr & 7)) << 3);
  }
  // ---- B staging: row=tid>>4 (+16/it), 8B granule g=tid&15; swizzle at LDS WRITE ----
  int brr = tid >> 4;
  int gB = tid & 15;
  int wofs = (((gB >> 1) ^ (brr & 7)) << 3) + ((gB & 1) << 2);   // u16 units in row
  long bbase[4];
#pragma unroll
  for (int it = 0; it < 4; ++it)
    bbase[it] = (long)(n0 + it * 16 + brr) * ldb + gB * 4;       // linear f32 source

  float4 r1[4], r3[4];

  auto stageA = [&](int buf, int k0) {
#pragma unroll
    for (int it = 0; it < 4; ++it)
      gload_lds16(A + abase[it] + k0, &As[buf][(it * 32 + sr) * 64 + scA * 8]);
  };
  auto loadB = [&](int k0) {
#pragma unroll
    for (int it = 0; it < 4; ++it) r1[it] = *(const float4*)(Bb1 + bbase[it] + k0);
    if (DUAL) {
#pragma unroll
      for (int it = 0; it < 4; ++it) r3[it] = *(const float4*)(Bb3 + bbase[it] + k0);
    }
  };
  auto writeB = [&](int buf) {
#pragma unroll
    for (int it = 0; it < 4; ++it) {
      int lo = (it * 16 + brr) * 64 + wofs;
      ushort4 o;
      o.x = f2bf(r1[it].x); o.y = f2bf(r1[it].y); o.z = f2bf(r1[it].z); o.w = f2bf(r1[it].w);
      *(ushort4*)&Bs1[buf][lo] = o;
      if (DUAL) {
        ushort4 q;
        q.x = f2bf(r3[it].x); q.y = f2bf(r3[it].y); q.z = f2bf(r3[it].z); q.w = f2bf(r3[it].w);
        *(ushort4*)&Bs3[buf][lo] = q;
      }
    }
  };

  loadB(0);          // 8 (dual) / 4 vm ops
  stageA(0, 0);      // 4 vm ops
  int NT = K >> 6;
  int cur = 0;
  for (int t = 0; t < NT; ++t) {
    int nxt = cur ^ 1;
    writeB(cur);                          // implicit vmcnt: B(t) regs ready; A(t) still flying
    if (t + 1 < NT) {
      loadB((t + 1) << 6);                // B(t+1) -> regs
      stageA(nxt, (t + 1) << 6);          // A(t+1) -> LDS[nxt]
      if (DUAL) asm volatile("s_waitcnt vmcnt(12)" ::: "memory");   // wait A(t) only
      else      asm volatile("s_waitcnt vmcnt(8)"  ::: "memory");
    } else {
      asm volatile("s_waitcnt vmcnt(0)" ::: "memory");              // tail: wait A(t)
    }
    asm volatile("s_waitcnt lgkmcnt(0)" ::: "memory");              // ds_writes visible
    __builtin_amdgcn_sched_barrier(0);
    __builtin_amdgcn_s_barrier();         // tile t fully in LDS for all waves
    __builtin_amdgcn_sched_barrier(0);
#pragma unroll
    for (int kk = 0; kk < 64; kk += 32) {
      short8 af[4], b1f[2], b3f[2];
#pragma unroll
      for (int i = 0; i < 4; ++i) {
        int R = wr * 64 + i * 16 + (lane & 15);
        int c = (kk >> 3) + (lane >> 4);
        af[i] = *(const short8*)&As[cur][R * 64 + ((c ^ (R & 7)) << 3)];
      }
#pragma unroll
      for (int i = 0; i < 2; ++i) {
        int r = wc * 32 + i * 16 + (lane & 15);
        int cR = (kk >> 3) + (lane >> 4);
        b1f[i] = *(const short8*)&Bs1[cur][r * 64 + ((cR ^ (r & 7)) << 3)];
        if (DUAL)
          b3f[i] = *(const short8*)&Bs3[cur][r * 64 + ((cR ^ (r & 7)) << 3)];
      }
#pragma unroll
      for (int mi = 0; mi < 4; ++mi)
#pragma unroll
        for (int ni = 0; ni < 2; ++ni) {
          acc1[mi][ni] = __builtin_amdgcn_mfma_f32_16x16x32_bf16(af[mi], b1f[ni], acc1[mi][ni], 0, 0, 0);
          if (DUAL)
            acc3[mi][ni] = __builtin_amdgcn_mfma_f32_16x16x32_bf16(af[mi], b3f[ni], acc3[mi][ni], 0, 0, 0);
        }
    }
    __builtin_amdgcn_sched_barrier(0);
    __builtin_amdgcn_s_barrier();         // all waves done reading buf[cur]
    cur = nxt;
  }

  int rbase = m0 + wr * 64 + (lane >> 4) * 4;
  int cbase = n0 + wc * 32 + (lane & 15);
#pragma unroll
  for (int mi = 0; mi < 4; ++mi) {
#pragma unroll
    for (int ni = 0; ni < 2; ++ni) {
      int col = cbase + ni * 16;
#pragma unroll
      for (int r = 0; r < 4; ++r) {
        int row = rbase + mi * 16 + r;
        float v = acc1[mi][ni][r];
        if (EPI == 0) {
          float a3 = acc3[mi][ni][r];
          float sg = v / (1.f + __expf(-v));
          Cb[(long)row * ldcb + col] = f2bf(sg * a3);
        } else if (EPI == 1) {
          C0[(long)row * ldc0 + col] = v;
        } else {
          if (row < rowlim) {
            atomicAdd(&C0[(long)perm[row] * ldc0 + col], v * pwt[row]);
          }
        }
      }
    }
  }
}

extern "C" void kernel_launch(void* const* d_in, const int* in_sizes, int n_in,
                              void* d_out, int out_size, void* d_ws, size_t ws_size,
                              hipStream_t stream) {
  (void)in_sizes; (void)n_in; (void)out_size; (void)ws_size;
  const float* x   = (const float*)d_in[0];
  const float* gw  = (const float*)d_in[1];
  const float* w1  = (const float*)d_in[2];
  const float* w2  = (const float*)d_in[3];
  const float* w3  = (const float*)d_in[4];
  const float* sw1 = (const float*)d_in[5];
  const float* sw2 = (const float*)d_in[6];
  const float* sw3 = (const float*)d_in[7];
  float* out = (float*)d_out;
  char* ws = (char*)d_ws;

  int*   counts = (int*)(ws + 0);
  int*   cursor = (int*)(ws + 64);
  int*   off    = (int*)(ws + 128);
  int*   cap    = (int*)(ws + 192);
  float* ssum   = (float*)(ws + 256);
  int*   tile2e = (int*)(ws + 1024);
  int*   tile2m0= (int*)(ws + 2048);
  int*   idxb   = (int*)(ws + 4096);
  float* wtb    = (float*)(ws + 4096 + 32768);
  int*   perm   = (int*)(ws + 4096 + 65536);
  float* pwt    = (float*)(ws + 4096 + 65536 + 40960);
  u16*   xb     = (u16*)(ws + 262144);                 // 2048x2048 bf16
  double* logits = (double*)(ws + 8650752);            // 2048x16 f64
  u16*   hbuf   = (u16*)(ws + 16777216);               // 10240x1408 bf16
  u16*   hsb    = (u16*)(ws + 45613056);               // 2048x2816 bf16

  hipMemsetAsync(ws, 0, 512, stream);
  gate_dots_kernel<<<dim3(NTOK), dim3(256), 0, stream>>>(x, gw, logits);
  topk_kernel<<<dim3(NTOK / 256), dim3(256), 0, stream>>>(logits, idxb, wtb, counts, ssum);
  setup_kernel<<<dim3(1), dim3(256), 0, stream>>>(counts, off, cap, ssum, perm, pwt,
                                                  out + AUX_IDX, tile2e, tile2m0);
  scatter_kernel<<<dim3(8), dim3(256), 0, stream>>>(idxb, wtb, off, cursor, perm, pwt);
  cvtN_kernel<<<dim3(2048), dim3(256), 0, stream>>>(x, xb, (long)NTOK * DIM);

  // routed h = silu(gather(x)@w1^T) * (gather(x)@w3^T) -> bf16
  gemm7_kernel<true, true, 0><<<dim3(MAXTILES, HID / 64), dim3(256), 0, stream>>>(
      xb, DIM, w1, w3, DIM, (long)HID * DIM, DIM, tile2e, tile2m0,
      off, counts, perm, pwt, nullptr, 0, hbuf, HID, 0);
  // shared hs = silu(x@sw1^T) * (x@sw3^T) -> bf16
  gemm7_kernel<false, true, 0><<<dim3(NTOK / 128, SHID / 64), dim3(256), 0, stream>>>(
      xb, DIM, sw1, sw3, DIM, 0, DIM, nullptr, nullptr,
      nullptr, nullptr, nullptr, nullptr, nullptr, 0, hsb, SHID, NTOK);
  // z = hs @ sw2^T  (plain f32 store into out)
  gemm7_kernel<false, false, 1><<<dim3(NTOK / 128, DIM / 64), dim3(256), 0, stream>>>(
      hsb, SHID, sw2, nullptr, SHID, 0, SHID, nullptr, nullptr,
      nullptr, nullptr, nullptr, nullptr, out, DIM, nullptr, 0, NTOK);
  // out += (h @ w2^T) * pwt   (atomic accumulate on top of z)
  gemm7_kernel<false, false, 2><<<dim3(MAXTILES, DIM / 64), dim3(256), 0, stream>>>(
      hbuf, HID, w2, nullptr, HID, (long)DIM * HID, HID, tile2e, tile2m0,
      off, counts, perm, pwt, out, DIM, nullptr, 0, 0);
}